// Round 8
// baseline (213.592 us; speedup 1.0000x reference)
//
#include <hip/hip_runtime.h>
#include <hip/hip_bf16.h>
#include <cstdint>

namespace {

constexpr int kB = 8;
constexpr int kS = 1024;
constexpr int kD = 768;
constexpr int kH = 12;
constexpr int kDH = 192;        // per-head qkv width in GEMM1 output space (q:64 k:64 v:64)
constexpr int kNQ = kH * kDH;   // 2304 (GEMM1 logical N)
constexpr int kNK = kH * 128;   // 1536 (compacted Q|K buffer stride)
constexpr int kM = kB * kS;     // 8192
constexpr int kDO = 768;

using f32x4 = __attribute__((ext_vector_type(4))) float;
using f32x16 = __attribute__((ext_vector_type(16))) float;
using s16x8 = __attribute__((ext_vector_type(8))) short;
using u16x8 = __attribute__((ext_vector_type(8))) unsigned short;
using u16x4 = __attribute__((ext_vector_type(4))) unsigned short;

__device__ __forceinline__ unsigned short f2bf(float f) {
  union { float f; uint32_t u; } v; v.f = f;
  uint32_t u = v.u;
  u += 0x7FFFu + ((u >> 16) & 1u);   // RNE
  return (unsigned short)(u >> 16);
}

__device__ __forceinline__ unsigned packbf(float a, float b) {
  return (unsigned)f2bf(a) | ((unsigned)f2bf(b) << 16);
}

__device__ __forceinline__ void load_lds16(const void* g, void* l) {
  __builtin_amdgcn_global_load_lds((__attribute__((address_space(1))) void*)g,
                                   (__attribute__((address_space(3))) void*)l,
                                   16, 0, 0);
}

// Build PV B-frag (8 bf16, one 16-k group) from own 8 P-values using verified
// primitives only (f2bf + shfl_xor). Own values (t-offsets per S^T C-layout):
//   hi=0 lanes: t {0,1, 2,3, 8,9, 10,11};  hi=1 lanes: t {4..7, 12..15}
// Needed: word j covers t = hi*8 + 2j, hi*8 + 2j+1.   [verified rounds 4-5]
__device__ __forceinline__ s16x8 repack8(int hi, float p0, float p1, float p2, float p3,
                                         float p4, float p5, float p6, float p7) {
  unsigned x0 = packbf(p0, p1);
  unsigned x1 = packbf(p2, p3);
  unsigned x2 = packbf(p4, p5);
  unsigned x3 = packbf(p6, p7);
  unsigned y0 = (unsigned)__shfl_xor((int)x0, 32, 64);
  unsigned y1 = (unsigned)__shfl_xor((int)x1, 32, 64);
  unsigned y2 = (unsigned)__shfl_xor((int)x2, 32, 64);
  unsigned y3 = (unsigned)__shfl_xor((int)x3, 32, 64);
  union { unsigned u[4]; s16x8 v; } r;
  r.u[0] = hi ? y2 : x0;   // t(0,1) | t(8,9)
  r.u[1] = hi ? y3 : x1;   // t(2,3) | t(10,11)
  r.u[2] = hi ? x2 : y0;   // t(4,5) | t(12,13)
  r.u[3] = hi ? x3 : y1;   // t(6,7) | t(14,15)
  return r.v;
}

// ---------------- prep kernels ----------------

__global__ __launch_bounds__(256) void cvt_x_kernel(const float* __restrict__ in,
                                                    unsigned short* __restrict__ out) {
  int i = (blockIdx.x * 256 + threadIdx.x) * 8;
  float4 a = *(const float4*)(in + i);
  float4 b = *(const float4*)(in + i + 4);
  u16x8 o;
  o[0] = f2bf(a.x); o[1] = f2bf(a.y); o[2] = f2bf(a.z); o[3] = f2bf(a.w);
  o[4] = f2bf(b.x); o[5] = f2bf(b.y); o[6] = f2bf(b.z); o[7] = f2bf(b.w);
  *(u16x8*)(out + i) = o;
}

// wt[n][k] = bf16(w[k][n]);  w is [K][N] f32
__global__ __launch_bounds__(256) void cvt_transpose_kernel(const float* __restrict__ w,
                                                            unsigned short* __restrict__ wt,
                                                            int K, int N) {
  __shared__ float tile[32][33];
  int k0 = blockIdx.x * 32, n0 = blockIdx.y * 32;
  int tx = threadIdx.x & 31, ty = threadIdx.x >> 5;  // 32 x 8
  #pragma unroll
  for (int r = 0; r < 32; r += 8)
    tile[ty + r][tx] = w[(size_t)(k0 + ty + r) * N + n0 + tx];
  __syncthreads();
  #pragma unroll
  for (int r = 0; r < 32; r += 8)
    wt[(size_t)(n0 + ty + r) * K + k0 + tx] = f2bf(tile[tx][ty + r]);
}

// ---------------- GEMM (m97 structure, B^T input, swapped-operand epilogue) -------------
// Main loop identical to verified rounds 2/4/5 EXCEPT mfma operand order is swapped:
//   acc = mfma(bfv[j], af[i], acc)  ->  D is transposed: reg-quad+g dim = n (B-tile
//   row of bfv = output col), la dim = m. Both fragments use the identical verified
//   loader, so this is a pure transpose of D — no new layout assumptions.
// MODE 0 epilogue: Q/K quads -> u16x4 store (4 consecutive cols); V -> 4 scalar
//   stores into Vtg[b][h][d][t] (d = quad dim, t = m).
// MODE 1 epilogue: float4 store + vectorized bias.
template <int MODE>
__global__ __launch_bounds__(256, 2) void gemm_bt_kernel(
    const unsigned short* __restrict__ A,   // [M][K] bf16
    const unsigned short* __restrict__ Bt,  // [N][K] bf16
    void* __restrict__ Cout,
    unsigned short* __restrict__ Vtg,       // MODE 0 only
    const float* __restrict__ bias,         // MODE 1 only
    int M, int N, int K) {
  __shared__ alignas(16) unsigned short Al[128 * 64];
  __shared__ alignas(16) unsigned short Bl[128 * 64];
  const int nT = N >> 7;
  // bijective XCD swizzle (T1; requires gridDim.x % 8 == 0 — holds: 1152 / 384)
  const int nwg = gridDim.x;
  const int bid = blockIdx.x;
  const int swz = (bid & 7) * (nwg >> 3) + (bid >> 3);
  const int tm = swz / nT, tn = swz % nT;
  const int tid = threadIdx.x;
  const int w = tid >> 6, l = tid & 63;
  const int wr = w >> 1, wc = w & 1;
  const int la = l & 15, g = l >> 4;
  const int sr = l >> 3, sc = l & 7;

  f32x4 acc[4][4] = {};
  const unsigned short* Ag = A + (size_t)(tm * 128) * K;
  const unsigned short* Bg = Bt + (size_t)(tn * 128) * K;

  for (int k0 = 0; k0 < K; k0 += 64) {
    #pragma unroll
    for (int j = 0; j < 4; ++j) {
      int row = w * 32 + j * 8 + sr;
      load_lds16(Ag + (size_t)row * K + k0 + sc * 8, &Al[row * 64 + sc * 8]);
      load_lds16(Bg + (size_t)row * K + k0 + sc * 8, &Bl[row * 64 + sc * 8]);
    }
    __syncthreads();
    #pragma unroll
    for (int kk = 0; kk < 2; ++kk) {
      s16x8 af[4], bfv[4];
      #pragma unroll
      for (int i = 0; i < 4; ++i)
        af[i] = *(const s16x8*)&Al[(wr * 64 + i * 16 + la) * 64 + kk * 32 + g * 8];
      #pragma unroll
      for (int j = 0; j < 4; ++j)
        bfv[j] = *(const s16x8*)&Bl[(wc * 64 + j * 16 + la) * 64 + kk * 32 + g * 8];
      #pragma unroll
      for (int i = 0; i < 4; ++i)
        #pragma unroll
        for (int j = 0; j < 4; ++j)
          acc[i][j] = __builtin_amdgcn_mfma_f32_16x16x32_bf16(bfv[j], af[i], acc[i][j], 0, 0, 0);
    }
    __syncthreads();
  }

  // D layout (swapped): m = tm*128 + wr*64 + i*16 + la ;
  //                     n = tn*128 + wc*64 + j*16 + g*4 + r  (r = reg)
  #pragma unroll
  for (int i = 0; i < 4; ++i) {
    int m = tm * 128 + wr * 64 + i * 16 + la;
    #pragma unroll
    for (int j = 0; j < 4; ++j) {
      int n0 = tn * 128 + wc * 64 + j * 16 + g * 4;
      if (MODE == 0) {
        int h = n0 / kDH, colm = n0 % kDH;  // 4-aligned quad never crosses 64-boundary
        if (colm < 128) {
          unsigned short* C = (unsigned short*)Cout;  // QK buf, stride kNK
          float sc2 = (colm < 64) ? 0.125f : 1.0f;    // fold 1/sqrt(DQK) into Q
          u16x4 pv;
          #pragma unroll
          for (int r = 0; r < 4; ++r) pv[r] = f2bf(acc[i][j][r] * sc2);
          *(u16x4*)&C[(size_t)m * kNK + h * 128 + colm] = pv;
        } else {
          int d0 = colm - 128;
          int bb = m >> 10, t = m & 1023;
          #pragma unroll
          for (int r = 0; r < 4; ++r)
            Vtg[((size_t)(bb * kH + h) * 64 + d0 + r) * kS + t] = f2bf(acc[i][j][r]);
        }
      } else {
        float* C = (float*)Cout;
        float4 bv = *(const float4*)&bias[n0];
        float4 o;
        o.x = acc[i][j][0] + bv.x; o.y = acc[i][j][1] + bv.y;
        o.z = acc[i][j][2] + bv.z; o.w = acc[i][j][3] + bv.w;
        *(float4*)&C[(size_t)m * N + n0] = o;
      }
    }
  }
}

// ---------------- fused attention — byte-exact round-5 version (verified) ----------------
// 4 waves x 32 q-rows (QBLK=128), KVBLK=64. S^T = mfma(K,Q): lane owns one q-row,
// 32 t-values in regs. In-register softmax (tree + shfl_xor(32)), f2bf+shfl repack,
// O^T = mfma(Vt,P). K/V double-buffered (T3 minimal).
__global__ __launch_bounds__(256, 3) void attn_kernel(
    const unsigned short* __restrict__ qk,    // [8192][1536] bf16 (Q pre-scaled | K)
    const unsigned short* __restrict__ Vtg,   // [8][12][64][1024] bf16 (V transposed)
    unsigned short* __restrict__ Ab) {        // [8192][768]  bf16
  const int id = blockIdx.x;
  const int b = id & 7;
  const int h = (id >> 3) % kH;
  const int qb = id / (kH * 8);
  const int tid = threadIdx.x;
  const int w = tid >> 6, l = tid & 63;
  const int q0 = l & 31, hi = l >> 5;

  __shared__ alignas(16) unsigned short Kl[2][64 * 64];
  __shared__ alignas(16) unsigned short Vl[2][64 * 64];  // V^T tiles: [d][t]

  const size_t base_bs = (size_t)b * kS;
  const size_t qrow0 = base_bs + (size_t)qb * 128;
  const size_t myq = qrow0 + w * 32 + q0;

  // Q fragments (B-operand): lane holds Q[q0][kg*16 + hi*8 + e]
  s16x8 qf[4];
  {
    const unsigned short* qp = qk + myq * kNK + h * 128 + hi * 8;
    #pragma unroll
    for (int kg = 0; kg < 4; ++kg) qf[kg] = *(const s16x8*)(qp + kg * 16);
  }

  // staging: 512 16B-chunks per tile, 2 issues/thread, linear LDS dest,
  // XOR swizzle on the GLOBAL source chunk (rule #21 / m173)
  const int c0 = w * 64 + l;
  const int c1 = 256 + w * 64 + l;
  const int r0 = c0 >> 3, cc0 = (c0 & 7) ^ (r0 & 7);
  const int r1 = c1 >> 3, cc1 = (c1 & 7) ^ (r1 & 7);
  const unsigned short* Kg = qk + base_bs * kNK + h * 128 + 64;
  const unsigned short* Vg = Vtg + (size_t)(b * kH + h) * 64 * kS;

  // 4 global_load_lds per thread per tile
  auto STAGE = [&](int buf, int kt) {
    load_lds16(Kg + (size_t)(kt * 64 + r0) * kNK + cc0 * 8, &Kl[buf][c0 * 8]);
    load_lds16(Kg + (size_t)(kt * 64 + r1) * kNK + cc1 * 8, &Kl[buf][c1 * 8]);
    load_lds16(Vg + (size_t)r0 * kS + kt * 64 + cc0 * 8, &Vl[buf][c0 * 8]);
    load_lds16(Vg + (size_t)r1 * kS + kt * 64 + cc1 * 8, &Vl[buf][c1 * 8]);
  };

  const float LOG2E = 1.44269504088896340736f;
  float m2 = -1e30f;   // running max, log2 domain
  float lrow = 0.f;
  f32x16 oacc[2] = {};

  // prologue
  STAGE(0, 0);
  asm volatile("s_waitcnt vmcnt(0)" ::: "memory");
  __builtin_amdgcn_s_barrier();
  __builtin_amdgcn_sched_barrier(0);

  int cur = 0;
  for (int kt = 0; kt < 16; ++kt) {
    // issue next tile's loads (safe: barrier at end of iter kt-1 postdates all
    // reads of the buffer these overwrite)
    if (kt < 15) STAGE(cur ^ 1, kt + 1);

    const unsigned short* Kc = &Kl[cur][0];
    const unsigned short* Vc = &Vl[cur][0];

    // S^T tiles: sacc[tb] covers t in [tb*32, tb*32+32), q = q0
    f32x16 sacc[2] = {};
    #pragma unroll
    for (int tb = 0; tb < 2; ++tb) {
      const int tl = tb * 32 + q0, xr = tl & 7;
      #pragma unroll
      for (int kg = 0; kg < 4; ++kg) {
        s16x8 kf = *(const s16x8*)&Kc[tl * 64 + (((kg * 2 + hi) ^ xr) * 8)];
        sacc[tb] = __builtin_amdgcn_mfma_f32_32x32x16_bf16(kf, qf[kg], sacc[tb], 0, 0, 0);
      }
    }

    // row max: in-register tree over own 32 values + one cross-half shfl
    float mx[16];
    #pragma unroll
    for (int r = 0; r < 16; ++r) mx[r] = fmaxf(sacc[0][r], sacc[1][r]);
    #pragma unroll
    for (int s2 = 8; s2 >= 1; s2 >>= 1)
      #pragma unroll
      for (int r = 0; r < s2; ++r) mx[r] = fmaxf(mx[r], mx[r + s2]);
    float pmax = fmaxf(mx[0], __shfl_xor(mx[0], 32, 64));
    float rx2 = pmax * LOG2E;
    // defer-max (T13): THR=8 natural = 11.54 in log2 domain
    if (!__all(rx2 - m2 <= 11.5416f)) {
      float m2n = fmaxf(m2, rx2);
      float corr = exp2f(m2 - m2n);
      m2 = m2n;
      lrow *= corr;
      #pragma unroll
      for (int db = 0; db < 2; ++db)
        #pragma unroll
        for (int r = 0; r < 16; ++r) oacc[db][r] *= corr;
    }

    float p[32];
    #pragma unroll
    for (int tb = 0; tb < 2; ++tb)
      #pragma unroll
      for (int r = 0; r < 16; ++r)
        p[tb * 16 + r] = exp2f(fmaf(sacc[tb][r], LOG2E, -m2));

    float sm[16];
    #pragma unroll
    for (int r = 0; r < 16; ++r) sm[r] = p[r] + p[16 + r];
    #pragma unroll
    for (int s2 = 8; s2 >= 1; s2 >>= 1)
      #pragma unroll
      for (int r = 0; r < s2; ++r) sm[r] += sm[r + s2];
    lrow += sm[0] + __shfl_xor(sm[0], 32, 64);

    // P -> B-frags, one per 16-t k-group
    s16x8 pb0 = repack8(hi, p[0], p[1], p[2], p[3], p[4], p[5], p[6], p[7]);
    s16x8 pb1 = repack8(hi, p[8], p[9], p[10], p[11], p[12], p[13], p[14], p[15]);
    s16x8 pb2 = repack8(hi, p[16], p[17], p[18], p[19], p[20], p[21], p[22], p[23]);
    s16x8 pb3 = repack8(hi, p[24], p[25], p[26], p[27], p[28], p[29], p[30], p[31]);

    // O^T += V^T P  (A = V^T rows d, B = P cols q)
    #pragma unroll
    for (int db = 0; db < 2; ++db) {
      const int dl = db * 32 + q0, xr = dl & 7;
      s16x8 v0 = *(const s16x8*)&Vc[dl * 64 + (((0 + hi) ^ xr) * 8)];
      s16x8 v1 = *(const s16x8*)&Vc[dl * 64 + (((2 + hi) ^ xr) * 8)];
      s16x8 v2 = *(const s16x8*)&Vc[dl * 64 + (((4 + hi) ^ xr) * 8)];
      s16x8 v3 = *(const s16x8*)&Vc[dl * 64 + (((6 + hi) ^ xr) * 8)];
      oacc[db] = __builtin_amdgcn_mfma_f32_32x32x16_bf16(v0, pb0, oacc[db], 0, 0, 0);
      oacc[db] = __builtin_amdgcn_mfma_f32_32x32x16_bf16(v1, pb1, oacc[db], 0, 0, 0);
      oacc[db] = __builtin_amdgcn_mfma_f32_32x32x16_bf16(v2, pb2, oacc[db], 0, 0, 0);
      oacc[db] = __builtin_amdgcn_mfma_f32_32x32x16_bf16(v3, pb3, oacc[db], 0, 0, 0);
    }

    // end-of-iter: wait own stage loads (hidden under the compute above), then
    // workgroup barrier -> next buffer fully staged & this buffer reusable
    __builtin_amdgcn_sched_barrier(0);
    asm volatile("s_waitcnt vmcnt(0)" ::: "memory");
    __builtin_amdgcn_s_barrier();
    __builtin_amdgcn_sched_barrier(0);
    cur ^= 1;
  }

  // epilogue: O^T reg r -> d = db*32 + 8*(r>>2) + 4*hi + (r&3); q = q0 (lane-local)
  float inv = 1.0f / lrow;
  unsigned short* dst = Ab + myq * (size_t)(kH * 64) + h * 64;
  #pragma unroll
  for (int db = 0; db < 2; ++db)
    #pragma unroll
    for (int rq = 0; rq < 4; ++rq) {
      u16x4 pv;
      #pragma unroll
      for (int j = 0; j < 4; ++j) pv[j] = f2bf(oacc[db][rq * 4 + j] * inv);
      *(u16x4*)&dst[db * 32 + rq * 8 + hi * 4] = pv;
    }
}

}  // namespace

extern "C" void kernel_launch(void* const* d_in, const int* in_sizes, int n_in,
                              void* d_out, int out_size, void* d_ws, size_t ws_size,
                              hipStream_t stream) {
  (void)in_sizes; (void)n_in; (void)out_size; (void)ws_size;
  const float* x = (const float*)d_in[0];
  const float* w_qkv = (const float*)d_in[1];
  const float* w_out = (const float*)d_in[2];
  const float* b_out = (const float*)d_in[3];

  unsigned short* Xb = (unsigned short*)d_ws;               // [8192][768]   12.6MB
  unsigned short* WqT = Xb + (size_t)kM * kD;               // [2304][768]    3.5MB
  unsigned short* WoT = WqT + (size_t)kNQ * kD;             // [768][768]     1.2MB
  unsigned short* QK = WoT + (size_t)kDO * kDO;             // [8192][1536]  25.2MB
  unsigned short* Vtg = QK + (size_t)kM * kNK;              // [96][64][1024] 12.6MB
  unsigned short* Ab = Vtg + (size_t)kB * kH * 64 * kS;     // [8192][768]   12.6MB

  cvt_x_kernel<<<dim3((kM * kD) / (256 * 8)), dim3(256), 0, stream>>>(x, Xb);
  cvt_transpose_kernel<<<dim3(kD / 32, kNQ / 32), dim3(256), 0, stream>>>(w_qkv, WqT, kD, kNQ);
  cvt_transpose_kernel<<<dim3(kDO / 32, kDO / 32), dim3(256), 0, stream>>>(w_out, WoT, kDO, kDO);

  gemm_bt_kernel<0><<<dim3((kM / 128) * (kNQ / 128)), dim3(256), 0, stream>>>(
      Xb, WqT, (void*)QK, Vtg, nullptr, kM, kNQ, kD);

  attn_kernel<<<dim3((kS / 128) * kH * kB), dim3(256), 0, stream>>>(QK, Vtg, Ab);

  gemm_bt_kernel<1><<<dim3((kM / 128) * (kDO / 128)), dim3(256), 0, stream>>>(
      Ab, WoT, d_out, nullptr, b_out, kM, kDO, kH * 64);
}

// Round 10
// 209.814 us; speedup vs baseline: 1.0180x; 1.0180x over previous
//
#include <hip/hip_runtime.h>
#include <hip/hip_bf16.h>
#include <cstdint>

namespace {

constexpr int kB = 8;
constexpr int kS = 1024;
constexpr int kD = 768;
constexpr int kH = 12;
constexpr int kDH = 192;        // per-head qkv width in GEMM1 output space (q:64 k:64 v:64)
constexpr int kNQ = kH * kDH;   // 2304 (GEMM1 logical N)
constexpr int kNK = kH * 128;   // 1536 (compacted Q|K buffer stride)
constexpr int kM = kB * kS;     // 8192
constexpr int kDO = 768;

using f32x4 = __attribute__((ext_vector_type(4))) float;
using f32x16 = __attribute__((ext_vector_type(16))) float;
using s16x8 = __attribute__((ext_vector_type(8))) short;
using u16x8 = __attribute__((ext_vector_type(8))) unsigned short;
using u16x4 = __attribute__((ext_vector_type(4))) unsigned short;

__device__ __forceinline__ unsigned short f2bf(float f) {
  union { float f; uint32_t u; } v; v.f = f;
  uint32_t u = v.u;
  u += 0x7FFFu + ((u >> 16) & 1u);   // RNE
  return (unsigned short)(u >> 16);
}

// packed f32->bf16 pair via documented HIP intrinsic (lo = a, hi = b, RNE) —
// compiler lowers to v_cvt_pk_bf16_f32 with guaranteed semantics.
__device__ __forceinline__ unsigned packbf(float a, float b) {
  float2 f; f.x = a; f.y = b;
  __hip_bfloat162 h = __float22bfloat162_rn(f);
  union { __hip_bfloat162 h; unsigned u; } c; c.h = h;
  return c.u;
}

__device__ __forceinline__ void load_lds16(const void* g, void* l) {
  __builtin_amdgcn_global_load_lds((__attribute__((address_space(1))) void*)g,
                                   (__attribute__((address_space(3))) void*)l,
                                   16, 0, 0);
}

// Build PV B-frag (8 bf16, one 16-k group) from own 8 P-values using verified
// primitives only (pack + shfl_xor). Own values (t-offsets per S^T C-layout):
//   hi=0 lanes: t {0,1, 2,3, 8,9, 10,11};  hi=1 lanes: t {4..7, 12..15}
// Needed: word j covers t = hi*8 + 2j, hi*8 + 2j+1.   [structure verified r4-r5/r8]
__device__ __forceinline__ s16x8 repack8(int hi, float p0, float p1, float p2, float p3,
                                         float p4, float p5, float p6, float p7) {
  unsigned x0 = packbf(p0, p1);
  unsigned x1 = packbf(p2, p3);
  unsigned x2 = packbf(p4, p5);
  unsigned x3 = packbf(p6, p7);
  unsigned y0 = (unsigned)__shfl_xor((int)x0, 32, 64);
  unsigned y1 = (unsigned)__shfl_xor((int)x1, 32, 64);
  unsigned y2 = (unsigned)__shfl_xor((int)x2, 32, 64);
  unsigned y3 = (unsigned)__shfl_xor((int)x3, 32, 64);
  union { unsigned u[4]; s16x8 v; } r;
  r.u[0] = hi ? y2 : x0;   // t(0,1) | t(8,9)
  r.u[1] = hi ? y3 : x1;   // t(2,3) | t(10,11)
  r.u[2] = hi ? x2 : y0;   // t(4,5) | t(12,13)
  r.u[3] = hi ? x3 : y1;   // t(6,7) | t(14,15)
  return r.v;
}

// ---------------- merged prep kernel ----------------
// blocks [0, 3072): x f32 -> bf16 (8 elems/thread)
// blocks [3072, 4800): transpose+cvt w_qkv [768][2304] -> WqT [2304][768]
// blocks [4800, 5376): transpose+cvt w_out [768][768] -> WoT [768][768]
__device__ __forceinline__ void transpose_tile(const float* __restrict__ w,
                                               unsigned short* __restrict__ wt,
                                               int K, int N, int k0, int n0,
                                               float (*tile)[33]) {
  int tx = threadIdx.x & 31, ty = threadIdx.x >> 5;  // 32 x 8
  #pragma unroll
  for (int r = 0; r < 32; r += 8)
    tile[ty + r][tx] = w[(size_t)(k0 + ty + r) * N + n0 + tx];
  __syncthreads();
  #pragma unroll
  for (int r = 0; r < 32; r += 8)
    wt[(size_t)(n0 + ty + r) * K + k0 + tx] = f2bf(tile[tx][ty + r]);
}

__global__ __launch_bounds__(256) void prep_kernel(const float* __restrict__ x,
                                                   const float* __restrict__ w_qkv,
                                                   const float* __restrict__ w_out,
                                                   unsigned short* __restrict__ Xb,
                                                   unsigned short* __restrict__ WqT,
                                                   unsigned short* __restrict__ WoT) {
  __shared__ float tile[32][33];
  int id = blockIdx.x;
  if (id < 3072) {
    int i = (id * 256 + threadIdx.x) * 8;
    float4 a = *(const float4*)(x + i);
    float4 b = *(const float4*)(x + i + 4);
    u16x8 o;
    o[0] = f2bf(a.x); o[1] = f2bf(a.y); o[2] = f2bf(a.z); o[3] = f2bf(a.w);
    o[4] = f2bf(b.x); o[5] = f2bf(b.y); o[6] = f2bf(b.z); o[7] = f2bf(b.w);
    *(u16x8*)(Xb + i) = o;
  } else if (id < 4800) {
    int t = id - 3072;                       // grid was (24, 72)
    transpose_tile(w_qkv, WqT, kD, kNQ, (t % 24) * 32, (t / 24) * 32, tile);
  } else {
    int t = id - 4800;                       // grid was (24, 24)
    transpose_tile(w_out, WoT, kDO, kDO, (t % 24) * 32, (t / 24) * 32, tile);
  }
}

// ---------------- GEMM (m97 structure, B^T input, swapped-operand epilogue) -------------
// Byte-identical to round-8 (verified passing).
template <int MODE>
__global__ __launch_bounds__(256, 2) void gemm_bt_kernel(
    const unsigned short* __restrict__ A,   // [M][K] bf16
    const unsigned short* __restrict__ Bt,  // [N][K] bf16
    void* __restrict__ Cout,
    unsigned short* __restrict__ Vtg,       // MODE 0 only
    const float* __restrict__ bias,         // MODE 1 only
    int M, int N, int K) {
  __shared__ alignas(16) unsigned short Al[128 * 64];
  __shared__ alignas(16) unsigned short Bl[128 * 64];
  const int nT = N >> 7;
  // bijective XCD swizzle (T1; requires gridDim.x % 8 == 0 — holds: 1152 / 384)
  const int nwg = gridDim.x;
  const int bid = blockIdx.x;
  const int swz = (bid & 7) * (nwg >> 3) + (bid >> 3);
  const int tm = swz / nT, tn = swz % nT;
  const int tid = threadIdx.x;
  const int w = tid >> 6, l = tid & 63;
  const int wr = w >> 1, wc = w & 1;
  const int la = l & 15, g = l >> 4;
  const int sr = l >> 3, sc = l & 7;

  f32x4 acc[4][4] = {};
  const unsigned short* Ag = A + (size_t)(tm * 128) * K;
  const unsigned short* Bg = Bt + (size_t)(tn * 128) * K;

  for (int k0 = 0; k0 < K; k0 += 64) {
    #pragma unroll
    for (int j = 0; j < 4; ++j) {
      int row = w * 32 + j * 8 + sr;
      load_lds16(Ag + (size_t)row * K + k0 + sc * 8, &Al[row * 64 + sc * 8]);
      load_lds16(Bg + (size_t)row * K + k0 + sc * 8, &Bl[row * 64 + sc * 8]);
    }
    __syncthreads();
    #pragma unroll
    for (int kk = 0; kk < 2; ++kk) {
      s16x8 af[4], bfv[4];
      #pragma unroll
      for (int i = 0; i < 4; ++i)
        af[i] = *(const s16x8*)&Al[(wr * 64 + i * 16 + la) * 64 + kk * 32 + g * 8];
      #pragma unroll
      for (int j = 0; j < 4; ++j)
        bfv[j] = *(const s16x8*)&Bl[(wc * 64 + j * 16 + la) * 64 + kk * 32 + g * 8];
      #pragma unroll
      for (int i = 0; i < 4; ++i)
        #pragma unroll
        for (int j = 0; j < 4; ++j)
          acc[i][j] = __builtin_amdgcn_mfma_f32_16x16x32_bf16(bfv[j], af[i], acc[i][j], 0, 0, 0);
    }
    __syncthreads();
  }

  // D layout (swapped): m = tm*128 + wr*64 + i*16 + la ;
  //                     n = tn*128 + wc*64 + j*16 + g*4 + r  (r = reg)
  #pragma unroll
  for (int i = 0; i < 4; ++i) {
    int m = tm * 128 + wr * 64 + i * 16 + la;
    #pragma unroll
    for (int j = 0; j < 4; ++j) {
      int n0 = tn * 128 + wc * 64 + j * 16 + g * 4;
      if (MODE == 0) {
        int h = n0 / kDH, colm = n0 % kDH;  // 4-aligned quad never crosses 64-boundary
        if (colm < 128) {
          unsigned short* C = (unsigned short*)Cout;  // QK buf, stride kNK
          float sc2 = (colm < 64) ? 0.125f : 1.0f;    // fold 1/sqrt(DQK) into Q
          u16x4 pv;
          #pragma unroll
          for (int r = 0; r < 4; ++r) pv[r] = f2bf(acc[i][j][r] * sc2);
          *(u16x4*)&C[(size_t)m * kNK + h * 128 + colm] = pv;
        } else {
          int d0 = colm - 128;
          int bb = m >> 10, t = m & 1023;
          #pragma unroll
          for (int r = 0; r < 4; ++r)
            Vtg[((size_t)(bb * kH + h) * 64 + d0 + r) * kS + t] = f2bf(acc[i][j][r]);
        }
      } else {
        float* C = (float*)Cout;
        float4 bv = *(const float4*)&bias[n0];
        float4 o;
        o.x = acc[i][j][0] + bv.x; o.y = acc[i][j][1] + bv.y;
        o.z = acc[i][j][2] + bv.z; o.w = acc[i][j][3] + bv.w;
        *(float4*)&C[(size_t)m * N + n0] = o;
      }
    }
  }
}

// ---------------- fused attention (32x32 swapped-QK^T, 2-phase dbuf) ----------------
// Identical to verified round-5/8 version EXCEPT packbf now uses the
// __float22bfloat162_rn intrinsic (same RNE values, ~10x fewer VALU ops).
__global__ __launch_bounds__(256, 3) void attn_kernel(
    const unsigned short* __restrict__ qk,    // [8192][1536] bf16 (Q pre-scaled | K)
    const unsigned short* __restrict__ Vtg,   // [8][12][64][1024] bf16 (V transposed)
    unsigned short* __restrict__ Ab) {        // [8192][768]  bf16
  const int id = blockIdx.x;
  const int b = id & 7;
  const int h = (id >> 3) % kH;
  const int qb = id / (kH * 8);
  const int tid = threadIdx.x;
  const int w = tid >> 6, l = tid & 63;
  const int q0 = l & 31, hi = l >> 5;

  __shared__ alignas(16) unsigned short Kl[2][64 * 64];
  __shared__ alignas(16) unsigned short Vl[2][64 * 64];  // V^T tiles: [d][t]

  const size_t base_bs = (size_t)b * kS;
  const size_t qrow0 = base_bs + (size_t)qb * 128;
  const size_t myq = qrow0 + w * 32 + q0;

  // Q fragments (B-operand): lane holds Q[q0][kg*16 + hi*8 + e]
  s16x8 qf[4];
  {
    const unsigned short* qp = qk + myq * kNK + h * 128 + hi * 8;
    #pragma unroll
    for (int kg = 0; kg < 4; ++kg) qf[kg] = *(const s16x8*)(qp + kg * 16);
  }

  // staging: 512 16B-chunks per tile, 2 issues/thread, linear LDS dest,
  // XOR swizzle on the GLOBAL source chunk (rule #21 / m173)
  const int c0 = w * 64 + l;
  const int c1 = 256 + w * 64 + l;
  const int r0 = c0 >> 3, cc0 = (c0 & 7) ^ (r0 & 7);
  const int r1 = c1 >> 3, cc1 = (c1 & 7) ^ (r1 & 7);
  const unsigned short* Kg = qk + base_bs * kNK + h * 128 + 64;
  const unsigned short* Vg = Vtg + (size_t)(b * kH + h) * 64 * kS;

  // 4 global_load_lds per thread per tile
  auto STAGE = [&](int buf, int kt) {
    load_lds16(Kg + (size_t)(kt * 64 + r0) * kNK + cc0 * 8, &Kl[buf][c0 * 8]);
    load_lds16(Kg + (size_t)(kt * 64 + r1) * kNK + cc1 * 8, &Kl[buf][c1 * 8]);
    load_lds16(Vg + (size_t)r0 * kS + kt * 64 + cc0 * 8, &Vl[buf][c0 * 8]);
    load_lds16(Vg + (size_t)r1 * kS + kt * 64 + cc1 * 8, &Vl[buf][c1 * 8]);
  };

  const float LOG2E = 1.44269504088896340736f;
  float m2 = -1e30f;   // running max, log2 domain
  float lrow = 0.f;
  f32x16 oacc[2] = {};

  // prologue
  STAGE(0, 0);
  asm volatile("s_waitcnt vmcnt(0)" ::: "memory");
  __builtin_amdgcn_s_barrier();
  __builtin_amdgcn_sched_barrier(0);

  int cur = 0;
  for (int kt = 0; kt < 16; ++kt) {
    // issue next tile's loads (safe: barrier at end of iter kt-1 postdates all
    // reads of the buffer these overwrite)
    if (kt < 15) STAGE(cur ^ 1, kt + 1);

    const unsigned short* Kc = &Kl[cur][0];
    const unsigned short* Vc = &Vl[cur][0];

    // S^T tiles: sacc[tb] covers t in [tb*32, tb*32+32), q = q0
    f32x16 sacc[2] = {};
    #pragma unroll
    for (int tb = 0; tb < 2; ++tb) {
      const int tl = tb * 32 + q0, xr = tl & 7;
      #pragma unroll
      for (int kg = 0; kg < 4; ++kg) {
        s16x8 kf = *(const s16x8*)&Kc[tl * 64 + (((kg * 2 + hi) ^ xr) * 8)];
        sacc[tb] = __builtin_amdgcn_mfma_f32_32x32x16_bf16(kf, qf[kg], sacc[tb], 0, 0, 0);
      }
    }

    // row max: in-register tree over own 32 values + one cross-half shfl
    float mx[16];
    #pragma unroll
    for (int r = 0; r < 16; ++r) mx[r] = fmaxf(sacc[0][r], sacc[1][r]);
    #pragma unroll
    for (int s2 = 8; s2 >= 1; s2 >>= 1)
      #pragma unroll
      for (int r = 0; r < s2; ++r) mx[r] = fmaxf(mx[r], mx[r + s2]);
    float pmax = fmaxf(mx[0], __shfl_xor(mx[0], 32, 64));
    float rx2 = pmax * LOG2E;
    // defer-max (T13): THR=8 natural = 11.54 in log2 domain
    if (!__all(rx2 - m2 <= 11.5416f)) {
      float m2n = fmaxf(m2, rx2);
      float corr = exp2f(m2 - m2n);
      m2 = m2n;
      lrow *= corr;
      #pragma unroll
      for (int db = 0; db < 2; ++db)
        #pragma unroll
        for (int r = 0; r < 16; ++r) oacc[db][r] *= corr;
    }

    float p[32];
    #pragma unroll
    for (int tb = 0; tb < 2; ++tb)
      #pragma unroll
      for (int r = 0; r < 16; ++r)
        p[tb * 16 + r] = exp2f(fmaf(sacc[tb][r], LOG2E, -m2));

    float sm[16];
    #pragma unroll
    for (int r = 0; r < 16; ++r) sm[r] = p[r] + p[16 + r];
    #pragma unroll
    for (int s2 = 8; s2 >= 1; s2 >>= 1)
      #pragma unroll
      for (int r = 0; r < s2; ++r) sm[r] += sm[r + s2];
    lrow += sm[0] + __shfl_xor(sm[0], 32, 64);

    // P -> B-frags, one per 16-t k-group
    s16x8 pb0 = repack8(hi, p[0], p[1], p[2], p[3], p[4], p[5], p[6], p[7]);
    s16x8 pb1 = repack8(hi, p[8], p[9], p[10], p[11], p[12], p[13], p[14], p[15]);
    s16x8 pb2 = repack8(hi, p[16], p[17], p[18], p[19], p[20], p[21], p[22], p[23]);
    s16x8 pb3 = repack8(hi, p[24], p[25], p[26], p[27], p[28], p[29], p[30], p[31]);

    // O^T += V^T P  (A = V^T rows d, B = P cols q)
    #pragma unroll
    for (int db = 0; db < 2; ++db) {
      const int dl = db * 32 + q0, xr = dl & 7;
      s16x8 v0 = *(const s16x8*)&Vc[dl * 64 + (((0 + hi) ^ xr) * 8)];
      s16x8 v1 = *(const s16x8*)&Vc[dl * 64 + (((2 + hi) ^ xr) * 8)];
      s16x8 v2 = *(const s16x8*)&Vc[dl * 64 + (((4 + hi) ^ xr) * 8)];
      s16x8 v3 = *(const s16x8*)&Vc[dl * 64 + (((6 + hi) ^ xr) * 8)];
      oacc[db] = __builtin_amdgcn_mfma_f32_32x32x16_bf16(v0, pb0, oacc[db], 0, 0, 0);
      oacc[db] = __builtin_amdgcn_mfma_f32_32x32x16_bf16(v1, pb1, oacc[db], 0, 0, 0);
      oacc[db] = __builtin_amdgcn_mfma_f32_32x32x16_bf16(v2, pb2, oacc[db], 0, 0, 0);
      oacc[db] = __builtin_amdgcn_mfma_f32_32x32x16_bf16(v3, pb3, oacc[db], 0, 0, 0);
    }

    // end-of-iter: wait own stage loads (hidden under the compute above), then
    // workgroup barrier -> next buffer fully staged & this buffer reusable
    __builtin_amdgcn_sched_barrier(0);
    asm volatile("s_waitcnt vmcnt(0)" ::: "memory");
    __builtin_amdgcn_s_barrier();
    __builtin_amdgcn_sched_barrier(0);
    cur ^= 1;
  }

  // epilogue: O^T reg r -> d = db*32 + 8*(r>>2) + 4*hi + (r&3); q = q0 (lane-local)
  float inv = 1.0f / lrow;
  unsigned short* dst = Ab + myq * (size_t)(kH * 64) + h * 64;
  #pragma unroll
  for (int db = 0; db < 2; ++db)
    #pragma unroll
    for (int rq = 0; rq < 4; ++rq) {
      union { unsigned u[2]; u16x4 v; } pk;
      pk.u[0] = packbf(oacc[db][rq * 4 + 0] * inv, oacc[db][rq * 4 + 1] * inv);
      pk.u[1] = packbf(oacc[db][rq * 4 + 2] * inv, oacc[db][rq * 4 + 3] * inv);
      *(u16x4*)&dst[db * 32 + rq * 8 + hi * 4] = pk.v;
    }
}

}  // namespace

extern "C" void kernel_launch(void* const* d_in, const int* in_sizes, int n_in,
                              void* d_out, int out_size, void* d_ws, size_t ws_size,
                              hipStream_t stream) {
  (void)in_sizes; (void)n_in; (void)out_size; (void)ws_size;
  const float* x = (const float*)d_in[0];
  const float* w_qkv = (const float*)d_in[1];
  const float* w_out = (const float*)d_in[2];
  const float* b_out = (const float*)d_in[3];

  unsigned short* Xb = (unsigned short*)d_ws;               // [8192][768]   12.6MB
  unsigned short* WqT = Xb + (size_t)kM * kD;               // [2304][768]    3.5MB
  unsigned short* WoT = WqT + (size_t)kNQ * kD;             // [768][768]     1.2MB
  unsigned short* QK = WoT + (size_t)kDO * kDO;             // [8192][1536]  25.2MB
  unsigned short* Vtg = QK + (size_t)kM * kNK;              // [96][64][1024] 12.6MB
  unsigned short* Ab = Vtg + (size_t)kB * kH * 64 * kS;     // [8192][768]   12.6MB

  prep_kernel<<<dim3(5376), dim3(256), 0, stream>>>(x, w_qkv, w_out, Xb, WqT, WoT);

  gemm_bt_kernel<0><<<dim3((kM / 128) * (kNQ / 128)), dim3(256), 0, stream>>>(
      Xb, WqT, (void*)QK, Vtg, nullptr, kM, kNQ, kD);

  attn_kernel<<<dim3((kS / 128) * kH * kB), dim3(256), 0, stream>>>(QK, Vtg, Ab);

  gemm_bt_kernel<1><<<dim3((kM / 128) * (kDO / 128)), dim3(256), 0, stream>>>(
      Ab, WoT, d_out, nullptr, b_out, kM, kDO, kH * 64);
}

// Round 11
// 208.272 us; speedup vs baseline: 1.0255x; 1.0074x over previous
//
#include <hip/hip_runtime.h>
#include <hip/hip_bf16.h>
#include <cstdint>

namespace {

constexpr int kB = 8;
constexpr int kS = 1024;
constexpr int kD = 768;
constexpr int kH = 12;
constexpr int kDH = 192;        // per-head qkv width in GEMM1 output space (q:64 k:64 v:64)
constexpr int kNQ = kH * kDH;   // 2304 (GEMM1 logical N)
constexpr int kNK = kH * 128;   // 1536 (compacted Q|K buffer stride)
constexpr int kM = kB * kS;     // 8192
constexpr int kDO = 768;

using f32x4 = __attribute__((ext_vector_type(4))) float;
using f32x16 = __attribute__((ext_vector_type(16))) float;
using s16x8 = __attribute__((ext_vector_type(8))) short;
using u16x8 = __attribute__((ext_vector_type(8))) unsigned short;
using u16x4 = __attribute__((ext_vector_type(4))) unsigned short;

__device__ __forceinline__ unsigned short f2bf(float f) {
  union { float f; uint32_t u; } v; v.f = f;
  uint32_t u = v.u;
  u += 0x7FFFu + ((u >> 16) & 1u);   // RNE
  return (unsigned short)(u >> 16);
}

// packed f32->bf16 pair via documented HIP intrinsic (lo = a, hi = b, RNE)
__device__ __forceinline__ unsigned packbf(float a, float b) {
  float2 f; f.x = a; f.y = b;
  __hip_bfloat162 h = __float22bfloat162_rn(f);
  union { __hip_bfloat162 h; unsigned u; } c; c.h = h;
  return c.u;
}

__device__ __forceinline__ void load_lds16(const void* g, void* l) {
  __builtin_amdgcn_global_load_lds((__attribute__((address_space(1))) void*)g,
                                   (__attribute__((address_space(3))) void*)l,
                                   16, 0, 0);
}

// Build PV B-frag (8 bf16, one 16-k group) from own 8 P-values using verified
// primitives only (pack + shfl_xor).   [structure verified r4/r5/r8/r10]
__device__ __forceinline__ s16x8 repack8(int hi, float p0, float p1, float p2, float p3,
                                         float p4, float p5, float p6, float p7) {
  unsigned x0 = packbf(p0, p1);
  unsigned x1 = packbf(p2, p3);
  unsigned x2 = packbf(p4, p5);
  unsigned x3 = packbf(p6, p7);
  unsigned y0 = (unsigned)__shfl_xor((int)x0, 32, 64);
  unsigned y1 = (unsigned)__shfl_xor((int)x1, 32, 64);
  unsigned y2 = (unsigned)__shfl_xor((int)x2, 32, 64);
  unsigned y3 = (unsigned)__shfl_xor((int)x3, 32, 64);
  union { unsigned u[4]; s16x8 v; } r;
  r.u[0] = hi ? y2 : x0;   // t(0,1) | t(8,9)
  r.u[1] = hi ? y3 : x1;   // t(2,3) | t(10,11)
  r.u[2] = hi ? x2 : y0;   // t(4,5) | t(12,13)
  r.u[3] = hi ? x3 : y1;   // t(6,7) | t(14,15)
  return r.v;
}

// ---------------- merged prep kernel (verified r10) ----------------
__device__ __forceinline__ void transpose_tile(const float* __restrict__ w,
                                               unsigned short* __restrict__ wt,
                                               int K, int N, int k0, int n0,
                                               float (*tile)[33]) {
  int tx = threadIdx.x & 31, ty = threadIdx.x >> 5;  // 32 x 8
  #pragma unroll
  for (int r = 0; r < 32; r += 8)
    tile[ty + r][tx] = w[(size_t)(k0 + ty + r) * N + n0 + tx];
  __syncthreads();
  #pragma unroll
  for (int r = 0; r < 32; r += 8)
    wt[(size_t)(n0 + ty + r) * K + k0 + tx] = f2bf(tile[tx][ty + r]);
}

__global__ __launch_bounds__(256) void prep_kernel(const float* __restrict__ x,
                                                   const float* __restrict__ w_qkv,
                                                   const float* __restrict__ w_out,
                                                   unsigned short* __restrict__ Xb,
                                                   unsigned short* __restrict__ WqT,
                                                   unsigned short* __restrict__ WoT) {
  __shared__ float tile[32][33];
  int id = blockIdx.x;
  if (id < 3072) {
    int i = (id * 256 + threadIdx.x) * 8;
    float4 a = *(const float4*)(x + i);
    float4 b = *(const float4*)(x + i + 4);
    u16x8 o;
    o[0] = f2bf(a.x); o[1] = f2bf(a.y); o[2] = f2bf(a.z); o[3] = f2bf(a.w);
    o[4] = f2bf(b.x); o[5] = f2bf(b.y); o[6] = f2bf(b.z); o[7] = f2bf(b.w);
    *(u16x8*)(Xb + i) = o;
  } else if (id < 4800) {
    int t = id - 3072;
    transpose_tile(w_qkv, WqT, kD, kNQ, (t % 24) * 32, (t / 24) * 32, tile);
  } else {
    int t = id - 4800;
    transpose_tile(w_out, WoT, kDO, kDO, (t % 24) * 32, (t / 24) * 32, tile);
  }
}

// ---------------- GEMM (m97 structure, B^T input, swapped-operand epilogue) -------------
// Byte-identical to round-8/10 (verified passing).
template <int MODE>
__global__ __launch_bounds__(256, 2) void gemm_bt_kernel(
    const unsigned short* __restrict__ A,   // [M][K] bf16
    const unsigned short* __restrict__ Bt,  // [N][K] bf16
    void* __restrict__ Cout,
    unsigned short* __restrict__ Vtg,       // MODE 0 only
    const float* __restrict__ bias,         // MODE 1 only
    int M, int N, int K) {
  __shared__ alignas(16) unsigned short Al[128 * 64];
  __shared__ alignas(16) unsigned short Bl[128 * 64];
  const int nT = N >> 7;
  const int nwg = gridDim.x;
  const int bid = blockIdx.x;
  const int swz = (bid & 7) * (nwg >> 3) + (bid >> 3);
  const int tm = swz / nT, tn = swz % nT;
  const int tid = threadIdx.x;
  const int w = tid >> 6, l = tid & 63;
  const int wr = w >> 1, wc = w & 1;
  const int la = l & 15, g = l >> 4;
  const int sr = l >> 3, sc = l & 7;

  f32x4 acc[4][4] = {};
  const unsigned short* Ag = A + (size_t)(tm * 128) * K;
  const unsigned short* Bg = Bt + (size_t)(tn * 128) * K;

  for (int k0 = 0; k0 < K; k0 += 64) {
    #pragma unroll
    for (int j = 0; j < 4; ++j) {
      int row = w * 32 + j * 8 + sr;
      load_lds16(Ag + (size_t)row * K + k0 + sc * 8, &Al[row * 64 + sc * 8]);
      load_lds16(Bg + (size_t)row * K + k0 + sc * 8, &Bl[row * 64 + sc * 8]);
    }
    __syncthreads();
    #pragma unroll
    for (int kk = 0; kk < 2; ++kk) {
      s16x8 af[4], bfv[4];
      #pragma unroll
      for (int i = 0; i < 4; ++i)
        af[i] = *(const s16x8*)&Al[(wr * 64 + i * 16 + la) * 64 + kk * 32 + g * 8];
      #pragma unroll
      for (int j = 0; j < 4; ++j)
        bfv[j] = *(const s16x8*)&Bl[(wc * 64 + j * 16 + la) * 64 + kk * 32 + g * 8];
      #pragma unroll
      for (int i = 0; i < 4; ++i)
        #pragma unroll
        for (int j = 0; j < 4; ++j)
          acc[i][j] = __builtin_amdgcn_mfma_f32_16x16x32_bf16(bfv[j], af[i], acc[i][j], 0, 0, 0);
    }
    __syncthreads();
  }

  // D layout (swapped): m = tm*128 + wr*64 + i*16 + la ;
  //                     n = tn*128 + wc*64 + j*16 + g*4 + r  (r = reg)
  #pragma unroll
  for (int i = 0; i < 4; ++i) {
    int m = tm * 128 + wr * 64 + i * 16 + la;
    #pragma unroll
    for (int j = 0; j < 4; ++j) {
      int n0 = tn * 128 + wc * 64 + j * 16 + g * 4;
      if (MODE == 0) {
        int h = n0 / kDH, colm = n0 % kDH;  // 4-aligned quad never crosses 64-boundary
        if (colm < 128) {
          unsigned short* C = (unsigned short*)Cout;  // QK buf, stride kNK
          float sc2 = (colm < 64) ? 0.125f : 1.0f;    // fold 1/sqrt(DQK) into Q
          u16x4 pv;
          #pragma unroll
          for (int r = 0; r < 4; ++r) pv[r] = f2bf(acc[i][j][r] * sc2);
          *(u16x4*)&C[(size_t)m * kNK + h * 128 + colm] = pv;
        } else {
          int d0 = colm - 128;
          int bb = m >> 10, t = m & 1023;
          #pragma unroll
          for (int r = 0; r < 4; ++r)
            Vtg[((size_t)(bb * kH + h) * 64 + d0 + r) * kS + t] = f2bf(acc[i][j][r]);
        }
      } else {
        float* C = (float*)Cout;
        float4 bv = *(const float4*)&bias[n0];
        float4 o;
        o.x = acc[i][j][0] + bv.x; o.y = acc[i][j][1] + bv.y;
        o.z = acc[i][j][2] + bv.z; o.w = acc[i][j][3] + bv.w;
        *(float4*)&C[(size_t)m * N + n0] = o;
      }
    }
  }
}

// ---------------- fused attention (8-wave KV-split, 32x32 swapped-QK^T, 2-phase dbuf) ----
// 512 threads = 8 waves: waves 0-3 (half=0) process t in [0,512), waves 4-7 (half=1)
// t in [512,1024), same 128 q-rows (wave-group member wg owns q-rows wg*32..+32).
// Per-wave loop body is the verified r10 code over 8 tiles on its half's own
// double-buffered LDS set. Final online-softmax merge through LDS.
__global__ __launch_bounds__(512, 4) void attn_kernel(
    const unsigned short* __restrict__ qk,    // [8192][1536] bf16 (Q pre-scaled | K)
    const unsigned short* __restrict__ Vtg,   // [8][12][64][1024] bf16 (V transposed)
    unsigned short* __restrict__ Ab) {        // [8192][768]  bf16
  const int id = blockIdx.x;
  const int b = id & 7;
  const int h = (id >> 3) % kH;
  const int qb = id / (kH * 8);
  const int tid = threadIdx.x;
  const int w = tid >> 6, l = tid & 63;
  const int wg = w & 3, half = w >> 2;
  const int q0 = l & 31, hi = l >> 5;

  __shared__ alignas(16) unsigned char smem[65536];
  // [half][buf] tiles of 4096 shorts each
  unsigned short* Kbase = (unsigned short*)smem;            // 2*2*4096 shorts = 32KB
  unsigned short* Vbase = (unsigned short*)(smem + 32768);  // 2*2*4096 shorts = 32KB

  const size_t base_bs = (size_t)b * kS;
  const size_t qrow0 = base_bs + (size_t)qb * 128;
  const size_t myq = qrow0 + wg * 32 + q0;

  // Q fragments (B-operand): lane holds Q[q0][kg*16 + hi*8 + e]
  s16x8 qf[4];
  {
    const unsigned short* qp = qk + myq * kNK + h * 128 + hi * 8;
    #pragma unroll
    for (int kg = 0; kg < 4; ++kg) qf[kg] = *(const s16x8*)(qp + kg * 16);
  }

  // staging: per half-group, 512 16B-chunks per tile, 2 issues/thread,
  // linear LDS dest, XOR swizzle on the GLOBAL source chunk (rule #21 / m173)
  const int c0 = wg * 64 + l;
  const int c1 = 256 + wg * 64 + l;
  const int r0 = c0 >> 3, cc0 = (c0 & 7) ^ (r0 & 7);
  const int r1 = c1 >> 3, cc1 = (c1 & 7) ^ (r1 & 7);
  const unsigned short* Kg = qk + base_bs * kNK + h * 128 + 64;
  const unsigned short* Vg = Vtg + (size_t)(b * kH + h) * 64 * kS;

  // 4 global_load_lds per thread per tile; ktg = global tile index
  auto STAGE = [&](int buf, int ktg) {
    unsigned short* Kd = Kbase + (half * 2 + buf) * 4096;
    unsigned short* Vd = Vbase + (half * 2 + buf) * 4096;
    load_lds16(Kg + (size_t)(ktg * 64 + r0) * kNK + cc0 * 8, Kd + c0 * 8);
    load_lds16(Kg + (size_t)(ktg * 64 + r1) * kNK + cc1 * 8, Kd + c1 * 8);
    load_lds16(Vg + (size_t)r0 * kS + ktg * 64 + cc0 * 8, Vd + c0 * 8);
    load_lds16(Vg + (size_t)r1 * kS + ktg * 64 + cc1 * 8, Vd + c1 * 8);
  };

  const float LOG2E = 1.44269504088896340736f;
  float m2 = -1e30f;   // running max, log2 domain
  float lrow = 0.f;
  f32x16 oacc[2] = {};

  // prologue
  STAGE(0, half * 8);
  asm volatile("s_waitcnt vmcnt(0)" ::: "memory");
  __builtin_amdgcn_s_barrier();
  __builtin_amdgcn_sched_barrier(0);

  int cur = 0;
  for (int kt = 0; kt < 8; ++kt) {
    if (kt < 7) STAGE(cur ^ 1, half * 8 + kt + 1);

    const unsigned short* Kc = Kbase + (half * 2 + cur) * 4096;
    const unsigned short* Vc = Vbase + (half * 2 + cur) * 4096;

    // S^T tiles: sacc[tb] covers local t in [tb*32, tb*32+32), q = q0
    f32x16 sacc[2] = {};
    __builtin_amdgcn_s_setprio(1);
    #pragma unroll
    for (int tb = 0; tb < 2; ++tb) {
      const int tl = tb * 32 + q0, xr = tl & 7;
      #pragma unroll
      for (int kg = 0; kg < 4; ++kg) {
        s16x8 kf = *(const s16x8*)&Kc[tl * 64 + (((kg * 2 + hi) ^ xr) * 8)];
        sacc[tb] = __builtin_amdgcn_mfma_f32_32x32x16_bf16(kf, qf[kg], sacc[tb], 0, 0, 0);
      }
    }
    __builtin_amdgcn_s_setprio(0);

    // row max: in-register tree over own 32 values + one cross-half shfl
    float mx[16];
    #pragma unroll
    for (int r = 0; r < 16; ++r) mx[r] = fmaxf(sacc[0][r], sacc[1][r]);
    #pragma unroll
    for (int s2 = 8; s2 >= 1; s2 >>= 1)
      #pragma unroll
      for (int r = 0; r < s2; ++r) mx[r] = fmaxf(mx[r], mx[r + s2]);
    float pmax = fmaxf(mx[0], __shfl_xor(mx[0], 32, 64));
    float rx2 = pmax * LOG2E;
    // defer-max (T13): THR=8 natural = 11.54 in log2 domain
    if (!__all(rx2 - m2 <= 11.5416f)) {
      float m2n = fmaxf(m2, rx2);
      float corr = exp2f(m2 - m2n);
      m2 = m2n;
      lrow *= corr;
      #pragma unroll
      for (int db = 0; db < 2; ++db)
        #pragma unroll
        for (int r = 0; r < 16; ++r) oacc[db][r] *= corr;
    }

    float p[32];
    #pragma unroll
    for (int tb = 0; tb < 2; ++tb)
      #pragma unroll
      for (int r = 0; r < 16; ++r)
        p[tb * 16 + r] = exp2f(fmaf(sacc[tb][r], LOG2E, -m2));

    float sm[16];
    #pragma unroll
    for (int r = 0; r < 16; ++r) sm[r] = p[r] + p[16 + r];
    #pragma unroll
    for (int s2 = 8; s2 >= 1; s2 >>= 1)
      #pragma unroll
      for (int r = 0; r < s2; ++r) sm[r] += sm[r + s2];
    lrow += sm[0] + __shfl_xor(sm[0], 32, 64);

    // P -> B-frags, one per 16-t k-group
    s16x8 pb0 = repack8(hi, p[0], p[1], p[2], p[3], p[4], p[5], p[6], p[7]);
    s16x8 pb1 = repack8(hi, p[8], p[9], p[10], p[11], p[12], p[13], p[14], p[15]);
    s16x8 pb2 = repack8(hi, p[16], p[17], p[18], p[19], p[20], p[21], p[22], p[23]);
    s16x8 pb3 = repack8(hi, p[24], p[25], p[26], p[27], p[28], p[29], p[30], p[31]);

    // O^T += V^T P  (A = V^T rows d, B = P cols q)
    __builtin_amdgcn_s_setprio(1);
    #pragma unroll
    for (int db = 0; db < 2; ++db) {
      const int dl = db * 32 + q0, xr = dl & 7;
      s16x8 v0 = *(const s16x8*)&Vc[dl * 64 + (((0 + hi) ^ xr) * 8)];
      s16x8 v1 = *(const s16x8*)&Vc[dl * 64 + (((2 + hi) ^ xr) * 8)];
      s16x8 v2 = *(const s16x8*)&Vc[dl * 64 + (((4 + hi) ^ xr) * 8)];
      s16x8 v3 = *(const s16x8*)&Vc[dl * 64 + (((6 + hi) ^ xr) * 8)];
      oacc[db] = __builtin_amdgcn_mfma_f32_32x32x16_bf16(v0, pb0, oacc[db], 0, 0, 0);
      oacc[db] = __builtin_amdgcn_mfma_f32_32x32x16_bf16(v1, pb1, oacc[db], 0, 0, 0);
      oacc[db] = __builtin_amdgcn_mfma_f32_32x32x16_bf16(v2, pb2, oacc[db], 0, 0, 0);
      oacc[db] = __builtin_amdgcn_mfma_f32_32x32x16_bf16(v3, pb3, oacc[db], 0, 0, 0);
    }
    __builtin_amdgcn_s_setprio(0);

    // end-of-iter: wait own stage loads, then workgroup barrier
    __builtin_amdgcn_sched_barrier(0);
    asm volatile("s_waitcnt vmcnt(0)" ::: "memory");
    __builtin_amdgcn_s_barrier();
    __builtin_amdgcn_sched_barrier(0);
    cur ^= 1;
  }

  // ---- merge the two KV-halves (online-softmax combine), then store ----
  // cbuf[wg][l] = 34 floats: O^T partial (32) + m2 + lrow, written by half=1.
  float* cbuf = (float*)smem;  // reuse LDS (all compute done past final barrier)
  if (half == 1) {
    float* dstb = cbuf + ((wg * 64 + l) * 34);
    #pragma unroll
    for (int db = 0; db < 2; ++db)
      #pragma unroll
      for (int r = 0; r < 16; ++r) dstb[db * 16 + r] = oacc[db][r];
    dstb[32] = m2;
    dstb[33] = lrow;
  }
  __syncthreads();
  if (half == 0) {
    const float* srcb = cbuf + ((wg * 64 + l) * 34);
    float m2p = srcb[32], lp = srcb[33];
    float mm = fmaxf(m2, m2p);
    float ca = exp2f(m2 - mm), cb2 = exp2f(m2p - mm);
    float inv = 1.0f / (lrow * ca + lp * cb2);
    float sa = ca * inv, sb = cb2 * inv;
    // epilogue: O^T reg r -> d = db*32 + 8*(r>>2) + 4*hi + (r&3); q = q0
    unsigned short* dst = Ab + myq * (size_t)(kH * 64) + h * 64;
    #pragma unroll
    for (int db = 0; db < 2; ++db)
      #pragma unroll
      for (int rq = 0; rq < 4; ++rq) {
        float v0 = oacc[db][rq * 4 + 0] * sa + srcb[db * 16 + rq * 4 + 0] * sb;
        float v1 = oacc[db][rq * 4 + 1] * sa + srcb[db * 16 + rq * 4 + 1] * sb;
        float v2 = oacc[db][rq * 4 + 2] * sa + srcb[db * 16 + rq * 4 + 2] * sb;
        float v3 = oacc[db][rq * 4 + 3] * sa + srcb[db * 16 + rq * 4 + 3] * sb;
        union { unsigned u[2]; u16x4 v; } pk;
        pk.u[0] = packbf(v0, v1);
        pk.u[1] = packbf(v2, v3);
        *(u16x4*)&dst[db * 32 + rq * 8 + hi * 4] = pk.v;
      }
  }
}

}  // namespace

extern "C" void kernel_launch(void* const* d_in, const int* in_sizes, int n_in,
                              void* d_out, int out_size, void* d_ws, size_t ws_size,
                              hipStream_t stream) {
  (void)in_sizes; (void)n_in; (void)out_size; (void)ws_size;
  const float* x = (const float*)d_in[0];
  const float* w_qkv = (const float*)d_in[1];
  const float* w_out = (const float*)d_in[2];
  const float* b_out = (const float*)d_in[3];

  unsigned short* Xb = (unsigned short*)d_ws;               // [8192][768]   12.6MB
  unsigned short* WqT = Xb + (size_t)kM * kD;               // [2304][768]    3.5MB
  unsigned short* WoT = WqT + (size_t)kNQ * kD;             // [768][768]     1.2MB
  unsigned short* QK = WoT + (size_t)kDO * kDO;             // [8192][1536]  25.2MB
  unsigned short* Vtg = QK + (size_t)kM * kNK;              // [96][64][1024] 12.6MB
  unsigned short* Ab = Vtg + (size_t)kB * kH * 64 * kS;     // [8192][768]   12.6MB

  prep_kernel<<<dim3(5376), dim3(256), 0, stream>>>(x, w_qkv, w_out, Xb, WqT, WoT);

  gemm_bt_kernel<0><<<dim3((kM / 128) * (kNQ / 128)), dim3(256), 0, stream>>>(
      Xb, WqT, (void*)QK, Vtg, nullptr, kM, kNQ, kD);

  attn_kernel<<<dim3((kS / 128) * kH * kB), dim3(512), 0, stream>>>(QK, Vtg, Ab);

  gemm_bt_kernel<1><<<dim3((kM / 128) * (kDO / 128)), dim3(256), 0, stream>>>(
      Ab, WoT, d_out, nullptr, b_out, kM, kDO, kH * 64);
}